// Round 1
// baseline (575.672 us; speedup 1.0000x reference)
//
#include <hip/hip_runtime.h>

#define J 10
#define P 16384
#define D 8
#define O 16
#define B 32

// One routing pass, fused:
//   logits = dot(u_hat, Vsum)  (Vsum = running sum of v's; 0 on pass 1 -> uniform softmax)
//   c = softmax_j(logits)
//   s[b,j,o] += sum_p c[b,j,p] * u_hat[b,j,p,o]
// u_hat recomputed on the fly from x, W (never materialized).
// Lane mapping: wave64 = 4 p-values x 16 o-lanes.
__global__ __launch_bounds__(256) void caps_pass(
    const float* __restrict__ x, const float* __restrict__ W,
    const float* __restrict__ Vsum, float* __restrict__ s_acc)
{
    const int b    = blockIdx.y;
    const int tid  = threadIdx.x;
    const int o    = tid & 15;         // lane bits 0-3
    const int psub = (tid >> 4) & 3;   // lane bits 4-5
    const int wave = tid >> 6;
    const int p_base = blockIdx.x * 256;

    // Vsum for this lane's o, all j (uniform across p-subgroups -> broadcast loads)
    float vs[J];
#pragma unroll
    for (int j = 0; j < J; ++j) vs[j] = Vsum[(b * J + j) * O + o];

    float acc[J];
#pragma unroll
    for (int j = 0; j < J; ++j) acc[j] = 0.f;

    for (int it = 0; it < 16; ++it) {
        const int p = p_base + it * 16 + wave * 4 + psub;

        // x[b,p,0:8] (same for the 16 o-lanes -> broadcast)
        const float4* xp = (const float4*)(x + ((size_t)b * P + p) * D);
        float4 x0 = xp[0], x1 = xp[1];
        float xv[8] = {x0.x, x0.y, x0.z, x0.w, x1.x, x1.y, x1.z, x1.w};

        // u_hat[j, o=mine] = sum_d x[d] * W[j,p,d,o]
        float uh[J];
        const float* Wl = W + (size_t)p * (D * O) + o;
#pragma unroll
        for (int j = 0; j < J; ++j) {
            const float* Wj = Wl + (size_t)j * P * D * O;
            float u = 0.f;
#pragma unroll
            for (int d = 0; d < D; ++d)
                u = fmaf(xv[d], Wj[d * O], u);
            uh[j] = u;
        }

        // logits: reduce uh[j]*vs[j] over the 16 o-lanes (butterfly)
        float lg[J];
#pragma unroll
        for (int j = 0; j < J; ++j) {
            float t = uh[j] * vs[j];
#pragma unroll
            for (int m = 1; m < 16; m <<= 1)
                t += __shfl_xor(t, m, 64);
            lg[j] = t;
        }

        // softmax over j (redundant in all lanes of the group; J=10)
        float mx = lg[0];
#pragma unroll
        for (int j = 1; j < J; ++j) mx = fmaxf(mx, lg[j]);
        float e[J];
        float Z = 0.f;
#pragma unroll
        for (int j = 0; j < J; ++j) { e[j] = __expf(lg[j] - mx); Z += e[j]; }
        float rZ = 1.f / Z;
#pragma unroll
        for (int j = 0; j < J; ++j) acc[j] = fmaf(e[j] * rZ, uh[j], acc[j]);
    }

    // reduce over the 4 p-subgroups within the wave (lane bits 4-5)
#pragma unroll
    for (int j = 0; j < J; ++j) {
        acc[j] += __shfl_xor(acc[j], 16, 64);
        acc[j] += __shfl_xor(acc[j], 32, 64);
    }

    // cross-wave reduce in LDS, then one atomicAdd per (j,o) per block
    __shared__ float lds[4][J * O];
    if ((tid & 63) < 16) {
#pragma unroll
        for (int j = 0; j < J; ++j) lds[wave][j * O + o] = acc[j];
    }
    __syncthreads();
    if (tid < J * O) {
        float v = lds[0][tid] + lds[1][tid] + lds[2][tid] + lds[3][tid];
        atomicAdd(&s_acc[b * (J * O) + tid], v);
    }
}

// v = squash(s); Vsum += v; zero s for next pass; optionally emit v.
// 16-lane group per (b,j) row.
__global__ __launch_bounds__(64) void caps_squash(
    float* __restrict__ s_acc, float* __restrict__ Vsum,
    float* __restrict__ out, int write_out)
{
    int row = blockIdx.x * 4 + (threadIdx.x >> 4); // 0..B*J-1
    int o = threadIdx.x & 15;
    float s = s_acc[row * O + o];
    float sq = s * s;
#pragma unroll
    for (int m = 1; m < 16; m <<= 1) sq += __shfl_xor(sq, m, 64);
    float scale = sqrtf(sq) / (1.f + sq);   // == |s|^2/((1+|s|^2)|s|)
    float v = s * scale;
    Vsum[row * O + o] += v;
    s_acc[row * O + o] = 0.f;
    if (write_out) out[row * O + o] = v;
}

__global__ __launch_bounds__(256) void caps_zero(float* __restrict__ ws)
{
    int i = blockIdx.x * 256 + threadIdx.x;
    if (i < 2 * B * J * O) ws[i] = 0.f;
}

extern "C" void kernel_launch(void* const* d_in, const int* in_sizes, int n_in,
                              void* d_out, int out_size, void* d_ws, size_t ws_size,
                              hipStream_t stream)
{
    const float* x = (const float*)d_in[0];
    const float* W = (const float*)d_in[1];
    float* out = (float*)d_out;

    float* s_acc = (float*)d_ws;              // B*J*O floats
    float* Vsum  = s_acc + B * J * O;         // B*J*O floats

    caps_zero<<<dim3(40), 256, 0, stream>>>(s_acc);   // zeros s_acc + Vsum (0xAA-poisoned)

    for (int it = 0; it < 3; ++it) {
        caps_pass<<<dim3(64, B), 256, 0, stream>>>(x, W, Vsum, s_acc);
        caps_squash<<<dim3(B * J / 4), 64, 0, stream>>>(s_acc, Vsum, out, it == 2 ? 1 : 0);
    }
}

// Round 2
// 508.982 us; speedup vs baseline: 1.1310x; 1.1310x over previous
//
#include <hip/hip_runtime.h>

#define J 10
#define P 16384
#define D 8
#define O 16
#define B 32

#define NBLK 512               // caps_pass grid.x (2 blocks/CU)
#define WPB 4                  // waves per block
#define SP (P / (NBLK * WPB))  // 8 p's per wave
#define SJO (B * J * O)        // 5120 = s[b][j][o] element count

// ---- DPP cross-lane helpers (VALU-speed, no LDS) ----
template <int CTRL>
__device__ __forceinline__ float dpp_mov_f(float v) {
    return __int_as_float(__builtin_amdgcn_update_dpp(
        0, __float_as_int(v), CTRL, 0xF, 0xF, true));
}
// sum across a 16-lane row; result broadcast to all 16 lanes
__device__ __forceinline__ float row_sum16(float v) {
    v += dpp_mov_f<0xB1>(v);   // quad_perm [1,0,3,2] : xor 1
    v += dpp_mov_f<0x4E>(v);   // quad_perm [2,3,0,1] : xor 2
    v += dpp_mov_f<0x124>(v);  // row_ror:4
    v += dpp_mov_f<0x128>(v);  // row_ror:8
    return v;
}

// One routing pass. Lane = (o in 0..15, bsub in 0..3). Each wave owns an
// 8-p strip and ALL 32 batches (bc loop x8, b = bc*4+bsub). W[j,p,:,o] is
// loaded into 80 VGPRs per p and reused across all 32 b -> W read once/pass.
// Logit o-reduction via DPP (no DS in hot loop). Per-block partial s written
// to s_part (no atomics).
__global__ __launch_bounds__(256, 2) void caps_pass(
    const float* __restrict__ x, const float* __restrict__ W,
    const float* __restrict__ Vsum, float* __restrict__ s_part)
{
    __shared__ float smem[6400];   // VsT[b][o][j] (stride 200/b, 12/o); reused as s_blk at flush
    const int tid  = threadIdx.x;
    const int o    = tid & 15;
    const int bsub = (tid >> 4) & 3;
    const int wid  = tid >> 6;

    // stage Vsum -> VsT[b][o][j] = smem[b*200 + o*12 + j] (padded: no 4-way bank alias)
    for (int i = tid; i < SJO; i += 256) {
        int b = i / (J * O);
        int r = i - b * (J * O);
        int j = r >> 4;
        int oo = r & 15;
        smem[b * 200 + oo * 12 + j] = Vsum[i];
    }
    __syncthreads();

    float acc[8][J];
#pragma unroll
    for (int bc = 0; bc < 8; ++bc)
#pragma unroll
        for (int j = 0; j < J; ++j) acc[bc][j] = 0.f;

    const int p0 = (blockIdx.x * WPB + wid) * SP;

#pragma unroll 1
    for (int pi = 0; pi < SP; ++pi) {
        const int p = p0 + pi;

        // W[j,p,d,o] for this lane's o: 80 scalar loads (64B-coalesced across o),
        // reused by all 32 batches below.
        float wv[J][D];
        const float* Wp = W + (size_t)p * (D * O) + o;
#pragma unroll
        for (int j = 0; j < J; ++j)
#pragma unroll
            for (int d = 0; d < D; ++d)
                wv[j][d] = Wp[(size_t)j * ((size_t)P * D * O) + d * O];

#pragma unroll
        for (int bc = 0; bc < 8; ++bc) {
            const int b = bc * 4 + bsub;

            const float4* xp = (const float4*)(x + ((size_t)b * P + p) * D);
            float4 xa = xp[0], xb = xp[1];
            float xv[8] = {xa.x, xa.y, xa.z, xa.w, xb.x, xb.y, xb.z, xb.w};

            float uh[J];
#pragma unroll
            for (int j = 0; j < J; ++j) {
                float u = 0.f;
#pragma unroll
                for (int d = 0; d < D; ++d) u = fmaf(xv[d], wv[j][d], u);
                uh[j] = u;
            }

            // vs[j] = Vsum[b][j][o] from LDS (vectorized, 16B-aligned)
            const float* vrow = &smem[b * 200 + o * 12];
            float vsj[12];
            *(float4*)&vsj[0] = *(const float4*)&vrow[0];
            *(float4*)&vsj[4] = *(const float4*)&vrow[4];
            *(float2*)&vsj[8] = *(const float2*)&vrow[8];

            float lg[J];
#pragma unroll
            for (int j = 0; j < J; ++j)
                lg[j] = row_sum16(uh[j] * vsj[j]);

            float mx = lg[0];
#pragma unroll
            for (int j = 1; j < J; ++j) mx = fmaxf(mx, lg[j]);
            float e[J], Z = 0.f;
#pragma unroll
            for (int j = 0; j < J; ++j) { e[j] = __expf(lg[j] - mx); Z += e[j]; }
            float rZ = __builtin_amdgcn_rcpf(Z);
#pragma unroll
            for (int j = 0; j < J; ++j)
                acc[bc][j] = fmaf(e[j] * rZ, uh[j], acc[bc][j]);
        }
    }

    // intra-block reduction into smem (VsT dead now), serialized over waves
    __syncthreads();
    for (int w = 0; w < WPB; ++w) {
        if (wid == w) {
#pragma unroll
            for (int bc = 0; bc < 8; ++bc) {
                int b = bc * 4 + bsub;
#pragma unroll
                for (int j = 0; j < J; ++j) {
                    int idx = (b * J + j) * O + o;
                    smem[idx] = (w == 0 ? 0.f : smem[idx]) + acc[bc][j];
                }
            }
        }
        __syncthreads();
    }

    float* dst = s_part + (size_t)blockIdx.x * SJO;
    for (int i = tid; i < SJO; i += 256) dst[i] = smem[i];
}

// Sum the NBLK per-block partials, squash, update Vsum, optionally emit v.
// One block per (b,j) row; 64 threads = 16 o-lanes x 4 partial-quarters.
__global__ __launch_bounds__(64) void caps_finish(
    const float* __restrict__ s_part, float* __restrict__ Vsum,
    float* __restrict__ out, int write_out)
{
    const int row = blockIdx.x;      // 0..B*J-1
    const int t = threadIdx.x;
    const int o = t & 15;
    const int q = t >> 4;
    const int GP = NBLK / 4;

    float s = 0.f;
    const float* src = s_part + row * O + o;
    for (int g = q * GP; g < (q + 1) * GP; ++g)
        s += src[(size_t)g * SJO];
    s += __shfl_xor(s, 16, 64);
    s += __shfl_xor(s, 32, 64);

    float sq = row_sum16(s * s);
    float v = s * (sqrtf(sq) / (1.f + sq));
    if (t < O) {
        Vsum[row * O + o] += v;
        if (write_out) out[row * O + o] = v;
    }
}

__global__ __launch_bounds__(256) void caps_zero(float* __restrict__ Vsum)
{
    int i = blockIdx.x * 256 + threadIdx.x;
    if (i < SJO) Vsum[i] = 0.f;
}

extern "C" void kernel_launch(void* const* d_in, const int* in_sizes, int n_in,
                              void* d_out, int out_size, void* d_ws, size_t ws_size,
                              hipStream_t stream)
{
    const float* x = (const float*)d_in[0];
    const float* W = (const float*)d_in[1];
    float* out = (float*)d_out;

    float* s_part = (float*)d_ws;                       // NBLK * 5120 floats (10.5 MB)
    float* Vsum   = s_part + (size_t)NBLK * SJO;        // 5120 floats

    caps_zero<<<dim3((SJO + 255) / 256), 256, 0, stream>>>(Vsum);

    for (int it = 0; it < 3; ++it) {
        caps_pass<<<dim3(NBLK), 256, 0, stream>>>(x, W, Vsum, s_part);
        caps_finish<<<dim3(B * J), 64, 0, stream>>>(s_part, Vsum, out, it == 2 ? 1 : 0);
    }
}

// Round 3
// 423.933 us; speedup vs baseline: 1.3579x; 1.2006x over previous
//
#include <hip/hip_runtime.h>

#define J 10
#define P 16384
#define D 8
#define O 16
#define B 32

#define WPB 4                    // waves per block
#define SP 8                     // p's per wave
#define PBLK (P / (WPB * SP))    // 512 p-blocks
#define BG 4                     // b-groups (8 b's each)
#define SJO (B * J * O)          // 5120
#define BSTRIDE 168              // LDS stride per local b (160 + 8 pad: no 4-way bank alias)

// ---- DPP cross-lane helpers (VALU-speed, no LDS) ----
template <int CTRL>
__device__ __forceinline__ float dpp_mov_f(float v) {
    return __int_as_float(__builtin_amdgcn_update_dpp(
        0, __float_as_int(v), CTRL, 0xF, 0xF, true));
}
// sum across a 16-lane row; result broadcast to all 16 lanes
__device__ __forceinline__ float row_sum16(float v) {
    v += dpp_mov_f<0xB1>(v);   // quad_perm xor 1
    v += dpp_mov_f<0x4E>(v);   // quad_perm xor 2
    v += dpp_mov_f<0x124>(v);  // row_ror:4
    v += dpp_mov_f<0x128>(v);  // row_ror:8
    return v;
}

// One routing pass. Grid = (p-blocks, 4 b-groups). Lane = (o:16, bsub:4);
// each wave owns an 8-p strip and 8 batches (bc in {0,1}, b = bg*8+bc*4+bsub).
// W[j,p,:,o] loaded in two j-halves of 5 (40 VGPRs) and reused across 8 b.
// vs (Vsum) is loop-invariant -> registers, loaded once. Pass 1 (first=1):
// c is uniformly 1/J, skip logits/softmax. acc[2][10] keeps live regs < 128.
__global__ __launch_bounds__(256, 4) void caps_pass(
    const float* __restrict__ x, const float* __restrict__ W,
    const float* __restrict__ Vsum, float* __restrict__ s_acc, int first)
{
    __shared__ float s_blk[WPB][8 * BSTRIDE];
    const int tid  = threadIdx.x;
    const int o    = tid & 15;
    const int bsub = (tid >> 4) & 3;
    const int wid  = tid >> 6;
    const int bg   = blockIdx.y;

    float vs[2][J];
    if (!first) {
#pragma unroll
        for (int bc = 0; bc < 2; ++bc) {
            const int b = bg * 8 + bc * 4 + bsub;
#pragma unroll
            for (int j = 0; j < J; ++j)
                vs[bc][j] = Vsum[(b * J + j) * O + o];
        }
    }

    float acc[2][J];
#pragma unroll
    for (int bc = 0; bc < 2; ++bc)
#pragma unroll
        for (int j = 0; j < J; ++j) acc[bc][j] = 0.f;

    const int p0 = (blockIdx.x * WPB + wid) * SP;

#pragma unroll 1
    for (int pi = 0; pi < SP; ++pi) {
        const int p = p0 + pi;
        float uh[2][J];

#pragma unroll
        for (int jh = 0; jh < 2; ++jh) {
            // W[j,p,d,o] for 5 j's (64B-coalesced across o; reused by 8 b's)
            float wv[5][D];
            const float* Wp = W + ((size_t)(jh * 5) * P + p) * (D * O) + o;
#pragma unroll
            for (int j5 = 0; j5 < 5; ++j5)
#pragma unroll
                for (int d = 0; d < D; ++d)
                    wv[j5][d] = Wp[(size_t)j5 * ((size_t)P * D * O) + d * O];

#pragma unroll
            for (int bc = 0; bc < 2; ++bc) {
                const int b = bg * 8 + bc * 4 + bsub;
                const float4* xp = (const float4*)(x + ((size_t)b * P + p) * D);
                const float4 xa = xp[0], xb = xp[1];
                const float xv[8] = {xa.x, xa.y, xa.z, xa.w,
                                     xb.x, xb.y, xb.z, xb.w};
#pragma unroll
                for (int j5 = 0; j5 < 5; ++j5) {
                    float u = 0.f;
#pragma unroll
                    for (int d = 0; d < D; ++d) u = fmaf(xv[d], wv[j5][d], u);
                    uh[bc][jh * 5 + j5] = u;
                }
            }
        }

        if (first) {
            const float cj = 1.0f / (float)J;
#pragma unroll
            for (int bc = 0; bc < 2; ++bc)
#pragma unroll
                for (int j = 0; j < J; ++j)
                    acc[bc][j] = fmaf(cj, uh[bc][j], acc[bc][j]);
        } else {
#pragma unroll
            for (int bc = 0; bc < 2; ++bc) {
                float lg[J];
#pragma unroll
                for (int j = 0; j < J; ++j)
                    lg[j] = row_sum16(uh[bc][j] * vs[bc][j]);
                float mx = lg[0];
#pragma unroll
                for (int j = 1; j < J; ++j) mx = fmaxf(mx, lg[j]);
                float e[J], Z = 0.f;
#pragma unroll
                for (int j = 0; j < J; ++j) { e[j] = __expf(lg[j] - mx); Z += e[j]; }
                const float rZ = __builtin_amdgcn_rcpf(Z);
#pragma unroll
                for (int j = 0; j < J; ++j)
                    acc[bc][j] = fmaf(e[j] * rZ, uh[bc][j], acc[bc][j]);
            }
        }
    }

    // per-wave partials -> LDS (2-way bank alias max, free)
#pragma unroll
    for (int bc = 0; bc < 2; ++bc) {
        const int bl = bc * 4 + bsub;
#pragma unroll
        for (int j = 0; j < J; ++j)
            s_blk[wid][bl * BSTRIDE + j * O + o] = acc[bc][j];
    }
    __syncthreads();

    // cross-wave sum + one atomicAdd per (b,j,o) per block (1280/block)
    for (int i = tid; i < 8 * J * O; i += 256) {
        const int bl = i / (J * O);
        const int r  = i - bl * (J * O);
        const float v = s_blk[0][bl * BSTRIDE + r] + s_blk[1][bl * BSTRIDE + r]
                      + s_blk[2][bl * BSTRIDE + r] + s_blk[3][bl * BSTRIDE + r];
        atomicAdd(&s_acc[(bg * 8 + bl) * (J * O) + r], v);
    }
}

// v = squash(s); Vsum += v; zero s_acc for next pass; optionally emit v.
__global__ __launch_bounds__(64) void caps_squash(
    float* __restrict__ s_acc, float* __restrict__ Vsum,
    float* __restrict__ out, int write_out)
{
    const int row = blockIdx.x * 4 + (threadIdx.x >> 4); // 0..B*J-1
    const int o = threadIdx.x & 15;
    float s = s_acc[row * O + o];
    float sq = s * s;
#pragma unroll
    for (int m = 1; m < 16; m <<= 1) sq += __shfl_xor(sq, m, 64);
    const float v = s * (sqrtf(sq) / (1.f + sq));   // == |s|^2/((1+|s|^2)|s|)
    Vsum[row * O + o] += v;
    s_acc[row * O + o] = 0.f;
    if (write_out) out[row * O + o] = v;
}

__global__ __launch_bounds__(256) void caps_zero(float* __restrict__ ws)
{
    const int i = blockIdx.x * 256 + threadIdx.x;
    if (i < 2 * SJO) ws[i] = 0.f;   // s_acc + Vsum
}

extern "C" void kernel_launch(void* const* d_in, const int* in_sizes, int n_in,
                              void* d_out, int out_size, void* d_ws, size_t ws_size,
                              hipStream_t stream)
{
    const float* x = (const float*)d_in[0];
    const float* W = (const float*)d_in[1];
    float* out = (float*)d_out;

    float* s_acc = (float*)d_ws;          // SJO floats
    float* Vsum  = s_acc + SJO;           // SJO floats

    caps_zero<<<dim3((2 * SJO + 255) / 256), 256, 0, stream>>>(s_acc);

    for (int it = 0; it < 3; ++it) {
        caps_pass<<<dim3(PBLK, BG), 256, 0, stream>>>(x, W, Vsum, s_acc, it == 0 ? 1 : 0);
        caps_squash<<<dim3(B * J / 4), 64, 0, stream>>>(s_acc, Vsum, out, it == 2 ? 1 : 0);
    }
}